// Round 1
// baseline (1221.900 us; speedup 1.0000x reference)
//
#include <hip/hip_runtime.h>
#include <math.h>

#define NUM_ENT 100000
#define NUM_EDGES 200000
#define DIM 768

typedef float f32x4 __attribute__((ext_vector_type(4)));
typedef __bf16 bf16x8 __attribute__((ext_vector_type(8)));
typedef unsigned int u32x4 __attribute__((ext_vector_type(4)));

// ---- ws layout (float indices) ----
#define WS_Y1    0        // 3*768
#define WS_CQ    2304     // 3*768
#define WS_QD    4608     // 3*32  (logits, softmaxed in place)
#define WS_HA    4704     // 3 hop_attn
#define WS_HOP1  4736     // 256
#define WS_CTX   4992     // 3*768
#define WS_B     7424     // bf16 frag-ordered: 1152 frags * 512 ushort = 294912 floats
#define WS_DPROB 302336   // 3*200000
#define WS_E     902336   // 4*100000

__device__ __forceinline__ unsigned short f2bf(float f) {
    unsigned int x = __builtin_bit_cast(unsigned int, f);
    x = x + 0x7fffu + ((x >> 16) & 1u);   // RTNE
    return (unsigned short)(x >> 16);
}
__device__ __forceinline__ float gelu_exact(float x) {
    return 0.5f * x * (1.0f + erff(x * 0.70710678118654752f));
}

// K1: y1[t][j] = gelu(q @ step_w1[t] + b1), plus hop1[s] = gelu(q @ hop_w1 + hb1)
__global__ void k1_layer1(const float* __restrict__ q, const float* __restrict__ sw1,
                          const float* __restrict__ sb1, const float* __restrict__ hw1,
                          const float* __restrict__ hb1, float* __restrict__ ws) {
    int o = blockIdx.x * 256 + threadIdx.x;
    if (o < 2304) {
        int t = o / DIM, j = o % DIM;
        const float* w = sw1 + (size_t)t * DIM * DIM + j;
        float acc = 0.f;
        for (int d = 0; d < DIM; ++d) acc += q[d] * w[(size_t)d * DIM];
        ws[WS_Y1 + o] = gelu_exact(acc + sb1[o]);
    } else if (o < 2560) {
        int s = o - 2304;
        const float* w = hw1 + s;
        float acc = 0.f;
        for (int d = 0; d < DIM; ++d) acc += q[d] * w[(size_t)d * 256];
        ws[WS_HOP1 + s] = gelu_exact(acc + hb1[s]);
    }
}

// K2: cq[t][j] = y1[t] @ step_w2[t] + b2
__global__ void k2_layer2(const float* __restrict__ sw2, const float* __restrict__ sb2,
                          float* __restrict__ ws) {
    int o = blockIdx.x * 256 + threadIdx.x;   // 0..2303
    int t = o / DIM, j = o % DIM;
    const float* w = sw2 + (size_t)t * DIM * DIM + j;
    const float* y = ws + WS_Y1 + t * DIM;
    float acc = 0.f;
    for (int d = 0; d < DIM; ++d) acc += y[d] * w[(size_t)d * DIM];
    ws[WS_CQ + o] = acc + sb2[o];
}

// K3: qlog[t][l] = dot(cq[t], qwh[l])
__global__ void k3_qlogits(const float* __restrict__ qwh, float* __restrict__ ws) {
    int b = blockIdx.x;               // 0..95
    int t = b >> 5, l = b & 31;
    int lane = threadIdx.x;           // 64
    const float* c = ws + WS_CQ + t * DIM;
    const float* w = qwh + l * DIM;
    float acc = 0.f;
    for (int i = lane; i < DIM; i += 64) acc += c[i] * w[i];
    for (int m = 32; m; m >>= 1) acc += __shfl_xor(acc, m);
    if (lane == 0) ws[WS_QD + b] = acc;
}

// K4: softmax qdist rows; hop logits + softmax -> hop_attn
__global__ void k4_small(const float* __restrict__ hw2, const float* __restrict__ hb2,
                         float* __restrict__ ws) {
    int lane = threadIdx.x;  // 64
    for (int t = 0; t < 3; ++t) {
        float v = (lane < 32) ? ws[WS_QD + t * 32 + lane] : -1e30f;
        float mx = v;
        for (int m = 1; m < 32; m <<= 1) mx = fmaxf(mx, __shfl_xor(mx, m, 32));
        float e = (lane < 32) ? expf(v - mx) : 0.f;
        float s = e;
        for (int m = 1; m < 32; m <<= 1) s += __shfl_xor(s, m, 32);
        if (lane < 32) ws[WS_QD + t * 32 + lane] = e / s;
    }
    float lg = 0.f;
    if (lane < 3) {
        for (int s = 0; s < 256; ++s) lg += ws[WS_HOP1 + s] * hw2[s * 3 + lane];
        lg += hb2[lane];
    }
    float l0 = __shfl(lg, 0), l1 = __shfl(lg, 1), l2 = __shfl(lg, 2);
    if (lane == 0) {
        float mx = fmaxf(l0, fmaxf(l1, l2));
        float e0 = expf(l0 - mx), e1 = expf(l1 - mx), e2 = expf(l2 - mx);
        float s = e0 + e1 + e2;
        ws[WS_HA + 0] = e0 / s; ws[WS_HA + 1] = e1 / s; ws[WS_HA + 2] = e2 / s;
    }
}

// K5: ctx[t][d] = cq[t][d] + sum_l qdist[t][l]*qwh[l][d]
__global__ void k5_ctx(const float* __restrict__ qwh, float* __restrict__ ws) {
    int o = blockIdx.x * 256 + threadIdx.x;  // 0..2303
    int t = o / DIM, d = o % DIM;
    float acc = ws[WS_CQ + o];
    const float* qd = ws + WS_QD + t * 32;
    for (int l = 0; l < 32; ++l) acc += qd[l] * qwh[l * DIM + d];
    ws[WS_CTX + o] = acc;
}

// K6: Bmat fragment-ordered bf16: frag f = (t*24+ks)*16+cf; lane holds 8 k's
// B[k][col] = ctx[t][k] * rel_w1[k][col],  k = ks*32+(lane>>4)*8+j, col = cf*16+(lane&15)
__global__ void k6_bmat(const float* __restrict__ rw1, float* __restrict__ ws) {
    int g = blockIdx.x * 256 + threadIdx.x;   // 0..73727
    int lane = g & 63, f = g >> 6;
    int cf = f & 15, tk = f >> 4;
    int t = tk / 24, ks = tk % 24;
    int k0 = ks * 32 + (lane >> 4) * 8;
    int col = cf * 16 + (lane & 15);
    const float* ctx = ws + WS_CTX + t * DIM;
    union { unsigned short u[8]; u32x4 v; } pk;
    #pragma unroll
    for (int j = 0; j < 8; ++j) {
        float v = ctx[k0 + j] * rw1[(size_t)(k0 + j) * 256 + col];
        pk.u[j] = f2bf(v);
    }
    *(u32x4*)((unsigned short*)(ws + WS_B) + (size_t)g * 8) = pk.v;
}

// K7: fused GEMM + epilogue -> dprob[t][edge]
// block: 64 edge rows, 512 threads = 8 waves (wm 0..3 over rows, wn 0..1 over 128-col halves)
__global__ __launch_bounds__(512)
void k7_gemm(const float* __restrict__ desc, const float* __restrict__ rb1,
             const float* __restrict__ rw2, const float* __restrict__ rb2,
             float* __restrict__ ws) {
    extern __shared__ unsigned short a_lds[];   // 96 KB: 96 frags * 64 lanes * 8 ushort
    __shared__ float part[2][64];
    const unsigned short* bmat = (const unsigned short*)(ws + WS_B);
    float* dprob = ws + WS_DPROB;
    int tid = threadIdx.x;
    int blk = blockIdx.x;

    // stage A (f32 -> bf16, fragment order)
    #pragma unroll
    for (int i = 0; i < 12; ++i) {
        int gf = i * 512 + tid;            // 0..6143
        int lane = gf & 63, f = gf >> 6;   // f = ks*4 + rf
        int rf = f & 3, ks = f >> 2;
        int row = rf * 16 + (lane & 15);
        int kb = ks * 32 + (lane >> 4) * 8;
        const float* src = desc + (size_t)(blk * 64 + row) * DIM + kb;
        float4 v0 = *(const float4*)src;
        float4 v1 = *(const float4*)(src + 4);
        union { unsigned short u[8]; u32x4 v; } pk;
        pk.u[0] = f2bf(v0.x); pk.u[1] = f2bf(v0.y); pk.u[2] = f2bf(v0.z); pk.u[3] = f2bf(v0.w);
        pk.u[4] = f2bf(v1.x); pk.u[5] = f2bf(v1.y); pk.u[6] = f2bf(v1.z); pk.u[7] = f2bf(v1.w);
        *(u32x4*)&a_lds[(size_t)gf * 8] = pk.v;
    }
    __syncthreads();

    int wid = tid >> 6, lane = tid & 63;
    int wm = wid >> 1, wn = wid & 1;
    float b1v[8], w2v[8];
    #pragma unroll
    for (int i = 0; i < 8; ++i) {
        int col = wn * 128 + i * 16 + (lane & 15);
        b1v[i] = rb1[col]; w2v[i] = rw2[col];
    }
    float b2 = rb2[0];

    for (int t = 0; t < 3; ++t) {
        f32x4 acc[8];
        #pragma unroll
        for (int i = 0; i < 8; ++i) acc[i] = f32x4{0.f, 0.f, 0.f, 0.f};
        for (int ks = 0; ks < 24; ++ks) {
            bf16x8 a = *(const bf16x8*)&a_lds[((size_t)(ks * 4 + wm) * 64 + lane) * 8];
            const unsigned short* bp = bmat + ((size_t)((t * 24 + ks) * 16 + wn * 8) * 64 + lane) * 8;
            #pragma unroll
            for (int i = 0; i < 8; ++i) {
                bf16x8 b = *(const bf16x8*)(bp + (size_t)i * 512);
                acc[i] = __builtin_amdgcn_mfma_f32_16x16x32_bf16(a, b, acc[i], 0, 0, 0);
            }
        }
        // epilogue: per row sum over cols of gelu(h + b1)*w2
        float rs[4] = {0.f, 0.f, 0.f, 0.f};
        #pragma unroll
        for (int i = 0; i < 8; ++i)
            #pragma unroll
            for (int r = 0; r < 4; ++r) {
                float h = acc[i][r] + b1v[i];
                rs[r] += gelu_exact(h) * w2v[i];
            }
        #pragma unroll
        for (int r = 0; r < 4; ++r)
            for (int m = 1; m < 16; m <<= 1) rs[r] += __shfl_xor(rs[r], m);
        if ((lane & 15) == 0) {
            int q = lane >> 4;
            #pragma unroll
            for (int r = 0; r < 4; ++r) part[wn][wm * 16 + q * 4 + r] = rs[r];
        }
        __syncthreads();
        if (tid < 64) {
            float v = part[0][tid] + part[1][tid] + b2;
            dprob[(size_t)t * NUM_EDGES + blk * 64 + tid] = 1.f / (1.f + expf(-v));
        }
        __syncthreads();
    }
}

// K8: init entity buffers e0..e3 (e0 gets topic 1.0s)
__global__ void k8_init(const int* __restrict__ topics, float* __restrict__ ws) {
    int i = blockIdx.x * 256 + threadIdx.x;
    if (i >= 4 * NUM_ENT) return;
    float v = 0.f;
    if (i < NUM_ENT) {
        if (i == topics[0] || i == topics[1] || i == topics[2] || i == topics[3]) v = 1.f;
    }
    ws[WS_E + i] = v;
}

// K9: scatter step t: e_{t+1}[obj] += e_t[sub] * dprob[t][e]
__global__ void k9_scatter(const int* __restrict__ kb, float* __restrict__ ws, int t) {
    int e = blockIdx.x * 256 + threadIdx.x;
    if (e >= NUM_EDGES) return;
    int sub = kb[2 * e], obj = kb[2 * e + 1];
    float p = ws[WS_E + (size_t)t * NUM_ENT + sub] * ws[WS_DPROB + (size_t)t * NUM_EDGES + e];
    if (p != 0.f) atomicAdd(&ws[WS_E + (size_t)(t + 1) * NUM_ENT + obj], p);
}

// K10: normalize e_{t+1}[i] = v / max(v, 1)
__global__ void k10_norm(float* __restrict__ ws, int t) {
    int i = blockIdx.x * 256 + threadIdx.x;
    if (i >= NUM_ENT) return;
    float* p = ws + WS_E + (size_t)(t + 1) * NUM_ENT;
    float v = p[i];
    p[i] = v / fmaxf(v, 1.f);
}

// K11: out[i] = sum_t hop_attn[t] * e_{t+1}[i]
__global__ void k11_out(const float* __restrict__ ws, float* __restrict__ out) {
    int i = blockIdx.x * 256 + threadIdx.x;
    if (i >= NUM_ENT) return;
    out[i] = ws[WS_HA + 0] * ws[WS_E + 1 * NUM_ENT + i]
           + ws[WS_HA + 1] * ws[WS_E + 2 * NUM_ENT + i]
           + ws[WS_HA + 2] * ws[WS_E + 3 * NUM_ENT + i];
}

extern "C" void kernel_launch(void* const* d_in, const int* in_sizes, int n_in,
                              void* d_out, int out_size, void* d_ws, size_t ws_size,
                              hipStream_t stream) {
    const float* q_emb   = (const float*)d_in[0];
    const float* qwh     = (const float*)d_in[1];
    const float* desc    = (const float*)d_in[2];
    const float* sw1     = (const float*)d_in[3];
    const float* sb1     = (const float*)d_in[4];
    const float* sw2     = (const float*)d_in[5];
    const float* sb2     = (const float*)d_in[6];
    const float* rw1     = (const float*)d_in[7];
    const float* rb1     = (const float*)d_in[8];
    const float* rw2     = (const float*)d_in[9];
    const float* rb2     = (const float*)d_in[10];
    const float* hw1     = (const float*)d_in[11];
    const float* hb1     = (const float*)d_in[12];
    const float* hw2     = (const float*)d_in[13];
    const float* hb2     = (const float*)d_in[14];
    const int*   kb      = (const int*)d_in[15];
    const int*   topics  = (const int*)d_in[16];
    float* ws  = (float*)d_ws;
    float* out = (float*)d_out;

    k8_init<<<(4 * NUM_ENT + 255) / 256, 256, 0, stream>>>(topics, ws);
    k1_layer1<<<10, 256, 0, stream>>>(q_emb, sw1, sb1, hw1, hb1, ws);
    k2_layer2<<<9, 256, 0, stream>>>(sw2, sb2, ws);
    k3_qlogits<<<96, 64, 0, stream>>>(qwh, ws);
    k4_small<<<1, 64, 0, stream>>>(hw2, hb2, ws);
    k5_ctx<<<9, 256, 0, stream>>>(qwh, ws);
    k6_bmat<<<288, 256, 0, stream>>>(rw1, ws);
    k7_gemm<<<NUM_EDGES / 64, 512, 98304, stream>>>(desc, rb1, rw2, rb2, ws);
    for (int t = 0; t < 3; ++t) {
        k9_scatter<<<(NUM_EDGES + 255) / 256, 256, 0, stream>>>(kb, ws, t);
        k10_norm<<<(NUM_ENT + 255) / 256, 256, 0, stream>>>(ws, t);
    }
    k11_out<<<(NUM_ENT + 255) / 256, 256, 0, stream>>>(ws, out);
}

// Round 2
// 645.971 us; speedup vs baseline: 1.8916x; 1.8916x over previous
//
#include <hip/hip_runtime.h>
#include <math.h>

#define NUM_ENT 100000
#define NUM_EDGES 200000
#define DIM 768
#define BM 96
#define KSTEPS 24

typedef float f32x4 __attribute__((ext_vector_type(4)));
typedef __bf16 bf16x8 __attribute__((ext_vector_type(8)));
typedef unsigned short u16x4 __attribute__((ext_vector_type(4)));

// ---- ws layout (float indices) ----
#define WS_Y1    0        // 3*768
#define WS_CQ    2304     // 3*768
#define WS_HA    4704     // 3 hop_attn
#define WS_HOP1  4736     // 256
#define WS_CTX   4992     // 3*768
#define WS_B     7424     // bf16 frag-ordered: 24 chunks * 48 frags * 1KB
#define WS_DPROB 302336   // 3*200000
#define WS_E     902336   // 4*100000

__device__ __forceinline__ unsigned short f2bf(float f) {
    unsigned int x = __builtin_bit_cast(unsigned int, f);
    x = x + 0x7fffu + ((x >> 16) & 1u);   // RTNE
    return (unsigned short)(x >> 16);
}

// A&S 7.1.26 erf approx, |eps| <= 1.5e-7
__device__ __forceinline__ float gelu_f(float x) {
    float z = 0.70710678118654752f * x;
    float s = fabsf(z);
    float t = 1.f / (1.f + 0.3275911f * s);
    float p = t * (0.254829592f + t * (-0.284496736f + t * (1.421413741f +
              t * (-1.453152027f + t * 1.061405429f))));
    float e = __expf(-s * s);
    float erfa = 1.f - p * e;
    erfa = copysignf(erfa, z);
    return 0.5f * x * (1.f + erfa);
}

__device__ __forceinline__ void gload16(const void* g, void* l) {
    __builtin_amdgcn_global_load_lds(
        (const __attribute__((address_space(1))) void*)g,
        (__attribute__((address_space(3))) void*)l, 16, 0, 0);
}

// K1: y1[t][j] = gelu(q @ step_w1[t] + b1); hop1[s] = gelu(q @ hop_w1 + hb1)
__global__ void k1_layer1(const float* __restrict__ q, const float* __restrict__ sw1,
                          const float* __restrict__ sb1, const float* __restrict__ hw1,
                          const float* __restrict__ hb1, float* __restrict__ ws) {
    int o = blockIdx.x * 256 + threadIdx.x;
    if (o < 2304) {
        int t = o / DIM, j = o % DIM;
        const float* w = sw1 + (size_t)t * DIM * DIM + j;
        float acc = 0.f;
        for (int d = 0; d < DIM; ++d) acc += q[d] * w[(size_t)d * DIM];
        ws[WS_Y1 + o] = gelu_f(acc + sb1[o]);
    } else if (o < 2560) {
        int s = o - 2304;
        const float* w = hw1 + s;
        float acc = 0.f;
        for (int d = 0; d < DIM; ++d) acc += q[d] * w[(size_t)d * 256];
        ws[WS_HOP1 + s] = gelu_f(acc + hb1[s]);
    }
}

// K2: cq[t][j] = y1[t] @ step_w2[t] + b2
__global__ void k2_layer2(const float* __restrict__ sw2, const float* __restrict__ sb2,
                          float* __restrict__ ws) {
    int o = blockIdx.x * 256 + threadIdx.x;   // 0..2303
    int t = o / DIM, j = o % DIM;
    const float* w = sw2 + (size_t)t * DIM * DIM + j;
    const float* y = ws + WS_Y1 + t * DIM;
    float acc = 0.f;
    for (int d = 0; d < DIM; ++d) acc += y[d] * w[(size_t)d * DIM];
    ws[WS_CQ + o] = acc + sb2[o];
}

// K345 (single block, 1024 thr): q_logits -> softmax -> ctx; hop_attn
__global__ void k345(const float* __restrict__ qwh, const float* __restrict__ hw2,
                     const float* __restrict__ hb2, float* __restrict__ ws) {
    __shared__ float qlog[96];
    int tid = threadIdx.x;
    int w = tid >> 6, lane = tid & 63;
    // phase 1: 96 dot products, 6 per wave
    for (int s = 0; s < 6; ++s) {
        int p = w * 6 + s;
        int t = p >> 5, l = p & 31;
        const float* c = ws + WS_CQ + t * DIM;
        const float* qw = qwh + l * DIM;
        float acc = 0.f;
        for (int i = lane; i < DIM; i += 64) acc += c[i] * qw[i];
        for (int m = 32; m; m >>= 1) acc += __shfl_xor(acc, m);
        if (lane == 0) qlog[p] = acc;
    }
    __syncthreads();
    // phase 2: softmax rows (in place in qlog); hop_attn
    if (tid < 64) {
        for (int t = 0; t < 3; ++t) {
            float v = (lane < 32) ? qlog[t * 32 + lane] : -1e30f;
            float mx = v;
            for (int m = 1; m < 32; m <<= 1) mx = fmaxf(mx, __shfl_xor(mx, m, 32));
            float e = (lane < 32) ? __expf(v - mx) : 0.f;
            float s = e;
            for (int m = 1; m < 32; m <<= 1) s += __shfl_xor(s, m, 32);
            if (lane < 32) qlog[t * 32 + lane] = e / s;
        }
        float lg = 0.f;
        if (lane < 3) {
            for (int s = 0; s < 256; ++s) lg += ws[WS_HOP1 + s] * hw2[s * 3 + lane];
            lg += hb2[lane];
        }
        float l0 = __shfl(lg, 0), l1 = __shfl(lg, 1), l2 = __shfl(lg, 2);
        if (lane == 0) {
            float mx = fmaxf(l0, fmaxf(l1, l2));
            float e0 = __expf(l0 - mx), e1 = __expf(l1 - mx), e2 = __expf(l2 - mx);
            float s = e0 + e1 + e2;
            ws[WS_HA + 0] = e0 / s; ws[WS_HA + 1] = e1 / s; ws[WS_HA + 2] = e2 / s;
        }
    }
    __syncthreads();
    // phase 3: ctx
    for (int o = tid; o < 2304; o += 1024) {
        int t = o / DIM, d = o % DIM;
        float acc = ws[WS_CQ + o];
        const float* qd = qlog + t * 32;
        for (int l = 0; l < 32; ++l) acc += qd[l] * qwh[l * DIM + d];
        ws[WS_CTX + o] = acc;
    }
}

// K6: B bf16, K-chunk-major frag order: chunk ks (0..23) holds 48 frags (t*16+cf)
__global__ void k6_bmat(const float* __restrict__ rw1, float* __restrict__ ws) {
    int g = blockIdx.x * 256 + threadIdx.x;   // 0..73727
    int lane = g & 63, f = g >> 6;            // f 0..1151
    int ks = f / 48, r = f % 48;
    int t = r >> 4, cf = r & 15;
    int k0 = ks * 32 + (lane >> 4) * 8;
    int col = cf * 16 + (lane & 15);
    const float* ctx = ws + WS_CTX + t * DIM;
    union { unsigned short u[8]; bf16x8 v; } pk;
    #pragma unroll
    for (int j = 0; j < 8; ++j) {
        float v = ctx[k0 + j] * rw1[(size_t)(k0 + j) * 256 + col];
        pk.u[j] = f2bf(v);
    }
    *(bf16x8*)((unsigned short*)(ws + WS_B) + (size_t)g * 8) = pk.v;
}

// K7: double-buffered LDS GEMM + fused epilogue -> dprob[t][edge]
// BM=96 rows, BN=768 (3t x 256), BK=32, 768 thr = 12 waves (t 0..2 x colgroup 0..3)
// LDS: abuf 2x6KB @0, bbuf 2x48KB @12288, part 12x96 f32 @110592  (total 115200)
__global__ __launch_bounds__(768, 3)
void k7_gemm(const float* __restrict__ desc, const float* __restrict__ rb1,
             const float* __restrict__ rw2, const float* __restrict__ rb2,
             float* __restrict__ ws) {
    extern __shared__ char lds[];
    unsigned short* aB = (unsigned short*)lds;              // 2 * 3072 ushort
    unsigned short* bB = (unsigned short*)(lds + 12288);    // 2 * 24576 ushort
    float* part = (float*)(lds + 110592);                   // 12 * 96

    const unsigned short* bmat = (const unsigned short*)(ws + WS_B);
    float* dprob = ws + WS_DPROB;
    int tid = threadIdx.x;
    int blk = blockIdx.x;
    int wid = tid >> 6, lane = tid & 63;
    int t = wid >> 2, cg = wid & 3;
    int fbase = t * 16 + cg * 4;

    // A staging indexing: thread -> (row, float4-quad)
    int arow = tid >> 3, aq = tid & 7;
    int rowg = blk * BM + arow;
    if (rowg > NUM_EDGES - 1) rowg = NUM_EDGES - 1;
    const float* asrc = desc + (size_t)rowg * DIM + aq * 4;
    int arf = arow >> 4, alr = arow & 15;
    int awoff = arf * 512 + (aq >> 1) * 128 + alr * 8 + (aq & 1) * 4; // ushort off

    // B staging indexing
    const char* bsrc0 = (const char*)bmat + wid * 4096 + lane * 16;
    char* bdst0 = (char*)bB + wid * 4096;

    f32x4 acc[6][4];
    #pragma unroll
    for (int rf = 0; rf < 6; ++rf)
        #pragma unroll
        for (int i = 0; i < 4; ++i) acc[rf][i] = f32x4{0.f, 0.f, 0.f, 0.f};

    // prologue: stage ks=0 into buf 0
    {
        float4 av = *(const float4*)asrc;
        #pragma unroll
        for (int j = 0; j < 4; ++j) gload16(bsrc0 + j * 1024, bdst0 + j * 1024);
        u16x4 pk;
        pk.x = f2bf(av.x); pk.y = f2bf(av.y); pk.z = f2bf(av.z); pk.w = f2bf(av.w);
        *(u16x4*)&aB[awoff] = pk;
    }
    __syncthreads();

    for (int ks = 0; ks < KSTEPS; ++ks) {
        int cur = ks & 1, nxt = cur ^ 1;
        float4 av;
        if (ks < KSTEPS - 1) {
            av = *(const float4*)(asrc + (ks + 1) * 32);
            const char* bs = bsrc0 + (size_t)(ks + 1) * 49152;
            char* bd = bdst0 + nxt * 49152;
            #pragma unroll
            for (int j = 0; j < 4; ++j) gload16(bs + j * 1024, bd + j * 1024);
        }
        const unsigned short* bb = bB + cur * 24576 + fbase * 512 + lane * 8;
        bf16x8 bfr[4];
        #pragma unroll
        for (int i = 0; i < 4; ++i) bfr[i] = *(const bf16x8*)(bb + i * 512);
        const unsigned short* ab = aB + cur * 3072 + lane * 8;
        #pragma unroll
        for (int rf = 0; rf < 6; ++rf) {
            bf16x8 a = *(const bf16x8*)(ab + rf * 512);
            #pragma unroll
            for (int i = 0; i < 4; ++i)
                acc[rf][i] = __builtin_amdgcn_mfma_f32_16x16x32_bf16(a, bfr[i], acc[rf][i], 0, 0, 0);
        }
        if (ks < KSTEPS - 1) {
            u16x4 pk;
            pk.x = f2bf(av.x); pk.y = f2bf(av.y); pk.z = f2bf(av.z); pk.w = f2bf(av.w);
            *(u16x4*)&aB[nxt * 3072 + awoff] = pk;
        }
        __syncthreads();
    }

    // epilogue: per-row sum over this wave's 64 cols of gelu(h+b1)*w2
    int col16 = lane & 15, quart = lane >> 4;
    float b1v[4], w2v[4];
    #pragma unroll
    for (int i = 0; i < 4; ++i) {
        int c = cg * 64 + i * 16 + col16;
        b1v[i] = rb1[c]; w2v[i] = rw2[c];
    }
    #pragma unroll
    for (int rf = 0; rf < 6; ++rf) {
        #pragma unroll
        for (int r = 0; r < 4; ++r) {
            float s = 0.f;
            #pragma unroll
            for (int i = 0; i < 4; ++i)
                s += gelu_f(acc[rf][i][r] + b1v[i]) * w2v[i];
            #pragma unroll
            for (int m = 1; m < 16; m <<= 1) s += __shfl_xor(s, m);
            if (col16 == 0) part[wid * 96 + rf * 16 + quart * 4 + r] = s;
        }
    }
    __syncthreads();
    if (tid < 288) {
        int tt = tid / 96, row = tid % 96;
        float v = part[(tt * 4 + 0) * 96 + row] + part[(tt * 4 + 1) * 96 + row]
                + part[(tt * 4 + 2) * 96 + row] + part[(tt * 4 + 3) * 96 + row] + rb2[0];
        float p = 1.f / (1.f + __expf(-v));
        int rg = blk * BM + row;
        if (rg < NUM_EDGES) dprob[(size_t)tt * NUM_EDGES + rg] = p;
    }
}

// K8: init entity buffers e0..e3 (e0 gets topic 1.0s)
__global__ void k8_init(const int* __restrict__ topics, float* __restrict__ ws) {
    int i = blockIdx.x * 256 + threadIdx.x;
    if (i >= 4 * NUM_ENT) return;
    float v = 0.f;
    if (i < NUM_ENT) {
        if (i == topics[0] || i == topics[1] || i == topics[2] || i == topics[3]) v = 1.f;
    }
    ws[WS_E + i] = v;
}

// K9: scatter step t: e_{t+1}[obj] += e_t[sub] * dprob[t][e]
__global__ void k9_scatter(const int* __restrict__ kb, float* __restrict__ ws, int t) {
    int e = blockIdx.x * 256 + threadIdx.x;
    if (e >= NUM_EDGES) return;
    int sub = kb[2 * e], obj = kb[2 * e + 1];
    float p = ws[WS_E + (size_t)t * NUM_ENT + sub] * ws[WS_DPROB + (size_t)t * NUM_EDGES + e];
    if (p != 0.f) atomicAdd(&ws[WS_E + (size_t)(t + 1) * NUM_ENT + obj], p);
}

// K10: normalize e_{t+1}; at t==2 also emit output
__global__ void k10_norm(float* __restrict__ ws, float* __restrict__ out, int t) {
    int i = blockIdx.x * 256 + threadIdx.x;
    if (i >= NUM_ENT) return;
    float* p = ws + WS_E + (size_t)(t + 1) * NUM_ENT;
    float v = p[i];
    v = v / fmaxf(v, 1.f);
    p[i] = v;
    if (t == 2) {
        out[i] = ws[WS_HA + 0] * ws[WS_E + 1 * NUM_ENT + i]
               + ws[WS_HA + 1] * ws[WS_E + 2 * NUM_ENT + i]
               + ws[WS_HA + 2] * v;
    }
}

extern "C" void kernel_launch(void* const* d_in, const int* in_sizes, int n_in,
                              void* d_out, int out_size, void* d_ws, size_t ws_size,
                              hipStream_t stream) {
    const float* q_emb   = (const float*)d_in[0];
    const float* qwh     = (const float*)d_in[1];
    const float* desc    = (const float*)d_in[2];
    const float* sw1     = (const float*)d_in[3];
    const float* sb1     = (const float*)d_in[4];
    const float* sw2     = (const float*)d_in[5];
    const float* sb2     = (const float*)d_in[6];
    const float* rw1     = (const float*)d_in[7];
    const float* rb1     = (const float*)d_in[8];
    const float* rw2     = (const float*)d_in[9];
    const float* rb2     = (const float*)d_in[10];
    const float* hw1     = (const float*)d_in[11];
    const float* hb1     = (const float*)d_in[12];
    const float* hw2     = (const float*)d_in[13];
    const float* hb2     = (const float*)d_in[14];
    const int*   kb      = (const int*)d_in[15];
    const int*   topics  = (const int*)d_in[16];
    float* ws  = (float*)d_ws;
    float* out = (float*)d_out;

    int nblk7 = (NUM_EDGES + BM - 1) / BM;   // 2084

    k8_init<<<(4 * NUM_ENT + 255) / 256, 256, 0, stream>>>(topics, ws);
    k1_layer1<<<10, 256, 0, stream>>>(q_emb, sw1, sb1, hw1, hb1, ws);
    k2_layer2<<<9, 256, 0, stream>>>(sw2, sb2, ws);
    k345<<<1, 1024, 0, stream>>>(qwh, hw2, hb2, ws);
    k6_bmat<<<288, 256, 0, stream>>>(rw1, ws);
    k7_gemm<<<nblk7, 768, 115200, stream>>>(desc, rb1, rw2, rb2, ws);
    for (int t = 0; t < 3; ++t) {
        k9_scatter<<<(NUM_EDGES + 255) / 256, 256, 0, stream>>>(kb, ws, t);
        k10_norm<<<(NUM_ENT + 255) / 256, 256, 0, stream>>>(ws, out, t);
    }
}

// Round 3
// 541.569 us; speedup vs baseline: 2.2562x; 1.1928x over previous
//
#include <hip/hip_runtime.h>
#include <math.h>

#define NUM_ENT 100000
#define NUM_EDGES 200000
#define DIM 768
#define BM 96
#define KSTEPS 24
#define NC 16
#define DCH 48

typedef float f32x4 __attribute__((ext_vector_type(4)));
typedef __bf16 bf16x8 __attribute__((ext_vector_type(8)));
typedef unsigned short u16x4 __attribute__((ext_vector_type(4)));

// ---- ws layout (float indices) ----
#define WS_Y1    0        // 3*768
#define WS_CQ    2304     // 3*768
#define WS_HA    4704     // 3 hop_attn
#define WS_HOP1  4736     // 256
#define WS_CTX   4992     // 3*768
#define WS_B     7424     // bf16 frag-ordered: 24 chunks * 48 frags * 1KB
#define WS_DPROB 302336   // 3*200000 (also transient home of P1/P2 partials)
#define WS_P1    302336   // 48*768
#define WS_P1H   339200   // 16*256
#define WS_P2    343296   // 48*768
#define WS_E     902336   // 4*100000 (slot 0 unused; e1..e3 raw sums)

__device__ __forceinline__ unsigned short f2bf(float f) {
    unsigned int x = __builtin_bit_cast(unsigned int, f);
    x = x + 0x7fffu + ((x >> 16) & 1u);   // RTNE
    return (unsigned short)(x >> 16);
}

// A&S 7.1.26 erf approx, |eps| <= 1.5e-7
__device__ __forceinline__ float gelu_f(float x) {
    float z = 0.70710678118654752f * x;
    float s = fabsf(z);
    float t = 1.f / (1.f + 0.3275911f * s);
    float p = t * (0.254829592f + t * (-0.284496736f + t * (1.421413741f +
              t * (-1.453152027f + t * 1.061405429f))));
    float e = __expf(-s * s);
    float erfa = copysignf(1.f - p * e, z);
    return 0.5f * x * (1.f + erfa);
}

__device__ __forceinline__ void gload16(const void* g, void* l) {
    __builtin_amdgcn_global_load_lds(
        (const __attribute__((address_space(1))) void*)g,
        (__attribute__((address_space(3))) void*)l, 16, 0, 0);
}

// K1a: d-split partials for step layer-1 (48 blocks) and hop layer-1 (16 blocks)
__global__ void k1a(const float* __restrict__ q, const float* __restrict__ sw1,
                    const float* __restrict__ hw1, float* __restrict__ ws) {
    int b = blockIdx.x, tid = threadIdx.x;
    if (b < 48) {
        int t = b >> 4, c = b & 15;
        const float* w = sw1 + (size_t)t * DIM * DIM + (size_t)c * DCH * DIM;
        float a0 = 0.f, a1 = 0.f, a2 = 0.f;
        for (int d = 0; d < DCH; ++d) {
            float qv = q[c * DCH + d];
            const float* wr = w + (size_t)d * DIM;
            a0 += qv * wr[tid]; a1 += qv * wr[tid + 256]; a2 += qv * wr[tid + 512];
        }
        float* p = ws + WS_P1 + (size_t)b * DIM;
        p[tid] = a0; p[tid + 256] = a1; p[tid + 512] = a2;
    } else {
        int c = b - 48;
        const float* w = hw1 + (size_t)c * DCH * 256;
        float a0 = 0.f;
        for (int d = 0; d < DCH; ++d) a0 += q[c * DCH + d] * w[(size_t)d * 256 + tid];
        ws[WS_P1H + c * 256 + tid] = a0;
    }
}

// K1b: reduce partials + bias + gelu -> y1, hop1
__global__ void k1b(const float* __restrict__ sb1, const float* __restrict__ hb1,
                    float* __restrict__ ws) {
    int o = blockIdx.x * 256 + threadIdx.x;
    if (o < 2304) {
        int t = o / DIM, j = o % DIM;
        float s = sb1[o];
        for (int c = 0; c < NC; ++c) s += ws[WS_P1 + (size_t)(t * 16 + c) * DIM + j];
        ws[WS_Y1 + o] = gelu_f(s);
    } else if (o < 2560) {
        int j = o - 2304;
        float s = hb1[j];
        for (int c = 0; c < NC; ++c) s += ws[WS_P1H + c * 256 + j];
        ws[WS_HOP1 + j] = gelu_f(s);
    }
}

// K2a: d-split partials for step layer-2
__global__ void k2a(const float* __restrict__ sw2, float* __restrict__ ws) {
    int b = blockIdx.x, tid = threadIdx.x;
    int t = b >> 4, c = b & 15;
    const float* w = sw2 + (size_t)t * DIM * DIM + (size_t)c * DCH * DIM;
    const float* y = ws + WS_Y1 + t * DIM + c * DCH;
    float a0 = 0.f, a1 = 0.f, a2 = 0.f;
    for (int d = 0; d < DCH; ++d) {
        float yv = y[d];
        const float* wr = w + (size_t)d * DIM;
        a0 += yv * wr[tid]; a1 += yv * wr[tid + 256]; a2 += yv * wr[tid + 512];
    }
    float* p = ws + WS_P2 + (size_t)b * DIM;
    p[tid] = a0; p[tid + 256] = a1; p[tid + 512] = a2;
}

// K2b: reduce -> cq
__global__ void k2b(const float* __restrict__ sb2, float* __restrict__ ws) {
    int o = blockIdx.x * 256 + threadIdx.x;   // 0..2303
    int t = o / DIM, j = o % DIM;
    float s = sb2[o];
    for (int c = 0; c < NC; ++c) s += ws[WS_P2 + (size_t)(t * 16 + c) * DIM + j];
    ws[WS_CQ + o] = s;
}

// K345 (single block, 1024 thr): q_logits -> softmax -> ctx; hop_attn
__global__ void k345(const float* __restrict__ qwh, const float* __restrict__ hw2,
                     const float* __restrict__ hb2, float* __restrict__ ws) {
    __shared__ float qlog[96];
    int tid = threadIdx.x;
    int w = tid >> 6, lane = tid & 63;
    for (int s = 0; s < 6; ++s) {
        int p = w * 6 + s;
        int t = p >> 5, l = p & 31;
        const float* c = ws + WS_CQ + t * DIM;
        const float* qw = qwh + l * DIM;
        float acc = 0.f;
        for (int i = lane; i < DIM; i += 64) acc += c[i] * qw[i];
        for (int m = 32; m; m >>= 1) acc += __shfl_xor(acc, m);
        if (lane == 0) qlog[p] = acc;
    }
    __syncthreads();
    if (tid < 64) {
        for (int t = 0; t < 3; ++t) {
            float v = (lane < 32) ? qlog[t * 32 + lane] : -1e30f;
            float mx = v;
            for (int m = 1; m < 32; m <<= 1) mx = fmaxf(mx, __shfl_xor(mx, m, 32));
            float e = (lane < 32) ? __expf(v - mx) : 0.f;
            float s = e;
            for (int m = 1; m < 32; m <<= 1) s += __shfl_xor(s, m, 32);
            if (lane < 32) qlog[t * 32 + lane] = e / s;
        }
        float lg = 0.f;
        if (lane < 3) {
            for (int s = 0; s < 256; ++s) lg += ws[WS_HOP1 + s] * hw2[s * 3 + lane];
            lg += hb2[lane];
        }
        float l0 = __shfl(lg, 0), l1 = __shfl(lg, 1), l2 = __shfl(lg, 2);
        if (lane == 0) {
            float mx = fmaxf(l0, fmaxf(l1, l2));
            float e0 = __expf(l0 - mx), e1 = __expf(l1 - mx), e2 = __expf(l2 - mx);
            float s = e0 + e1 + e2;
            ws[WS_HA + 0] = e0 / s; ws[WS_HA + 1] = e1 / s; ws[WS_HA + 2] = e2 / s;
        }
    }
    __syncthreads();
    for (int o = tid; o < 2304; o += 1024) {
        int t = o / DIM, d = o % DIM;
        float acc = ws[WS_CQ + o];
        const float* qd = qlog + t * 32;
        for (int l = 0; l < 32; ++l) acc += qd[l] * qwh[l * DIM + d];
        ws[WS_CTX + o] = acc;
    }
}

// K6: B bf16, K-chunk-major frag order: chunk ks (0..23) holds 48 frags (t*16+cf)
__global__ void k6_bmat(const float* __restrict__ rw1, float* __restrict__ ws) {
    int g = blockIdx.x * 256 + threadIdx.x;   // 0..73727
    int lane = g & 63, f = g >> 6;            // f 0..1151
    int ks = f / 48, r = f % 48;
    int t = r >> 4, cf = r & 15;
    int k0 = ks * 32 + (lane >> 4) * 8;
    int col = cf * 16 + (lane & 15);
    const float* ctx = ws + WS_CTX + t * DIM;
    union { unsigned short u[8]; bf16x8 v; } pk;
    #pragma unroll
    for (int j = 0; j < 8; ++j) {
        float v = ctx[k0 + j] * rw1[(size_t)(k0 + j) * 256 + col];
        pk.u[j] = f2bf(v);
    }
    *(bf16x8*)((unsigned short*)(ws + WS_B) + (size_t)g * 8) = pk.v;
}

// K7: counted-vmcnt pipelined GEMM + fused epilogue -> dprob[t][edge]
// BM=96, BN=768 (3t x 256), BK=32, 768 thr = 12 waves (wid = t*4+cg).
// Key invariant: wave wid consumes exactly the B frags it stages (fbase==4*wid),
// so B needs NO barrier; counted vmcnt keeps B-DMA in flight across the A-barrier.
// LDS: bbuf 2x48KB @0, abuf 2x6KB @98304, part 12x96 f32 @110592 (115200 B)
__global__ __launch_bounds__(768, 3)
void k7_gemm(const float* __restrict__ desc, const float* __restrict__ rb1,
             const float* __restrict__ rw2, const float* __restrict__ rb2,
             float* __restrict__ ws) {
    extern __shared__ char lds[];
    unsigned short* bB = (unsigned short*)lds;               // 2 * 24576 ushort
    unsigned short* aB = (unsigned short*)(lds + 98304);     // 2 * 3072 ushort
    float* part = (float*)(lds + 110592);                    // 12 * 96

    const unsigned short* bmat = (const unsigned short*)(ws + WS_B);
    float* dprob = ws + WS_DPROB;
    int tid = threadIdx.x;
    int blk = blockIdx.x;
    int wid = tid >> 6, lane = tid & 63;
    int t = wid >> 2, cg = wid & 3;
    int fbase = t * 16 + cg * 4;   // == 4*wid

    // A staging indexing: thread -> (row, float4-quad)
    int arow = tid >> 3, aq = tid & 7;
    int rowg = blk * BM + arow;
    if (rowg > NUM_EDGES - 1) rowg = NUM_EDGES - 1;
    const float* asrc = desc + (size_t)rowg * DIM + aq * 4;
    int arf = arow >> 4, alr = arow & 15;
    int awoff = arf * 512 + (aq >> 1) * 128 + alr * 8 + (aq & 1) * 4; // ushort off

    // B staging: wave-uniform LDS base; per-lane global source
    const char* bsrc0 = (const char*)bmat + wid * 4096 + lane * 16;
    char* bdst0 = (char*)bB + wid * 4096;

    f32x4 acc[6][4];
    #pragma unroll
    for (int rf = 0; rf < 6; ++rf)
        #pragma unroll
        for (int i = 0; i < 4; ++i) acc[rf][i] = f32x4{0.f, 0.f, 0.f, 0.f};

    // prologue: A(0) reg-load first, then B(0) DMA (so compiler's av wait is vmcnt(4))
    {
        float4 av = *(const float4*)asrc;
        #pragma unroll
        for (int j = 0; j < 4; ++j) gload16(bsrc0 + j * 1024, bdst0 + j * 1024);
        u16x4 pk;
        pk.x = f2bf(av.x); pk.y = f2bf(av.y); pk.z = f2bf(av.z); pk.w = f2bf(av.w);
        *(u16x4*)&aB[awoff] = pk;
    }
    asm volatile("s_waitcnt lgkmcnt(0)" ::: "memory");
    __builtin_amdgcn_s_barrier();

    #pragma unroll 1
    for (int ks = 0; ks < KSTEPS; ++ks) {
        int cur = ks & 1, nxt = cur ^ 1;
        float4 av;
        if (ks < KSTEPS - 1) {
            av = *(const float4*)(asrc + (ks + 1) * 32);           // oldest this iter
            const char* bs = bsrc0 + (size_t)(ks + 1) * 49152;
            char* bd = bdst0 + nxt * 49152;
            #pragma unroll
            for (int j = 0; j < 4; ++j) gload16(bs + j * 1024, bd + j * 1024);
            // outstanding: B(ks) x4 (oldest) + av + B(ks+1) x4 -> keep 5 in flight
            asm volatile("s_waitcnt vmcnt(5)" ::: "memory");
        } else {
            asm volatile("s_waitcnt vmcnt(0)" ::: "memory");
        }
        __builtin_amdgcn_sched_barrier(0);

        const unsigned short* bb = bB + cur * 24576 + fbase * 512 + lane * 8;
        bf16x8 bfr[4];
        #pragma unroll
        for (int i = 0; i < 4; ++i) bfr[i] = *(const bf16x8*)(bb + i * 512);
        const unsigned short* ab = aB + cur * 3072 + lane * 8;

        __builtin_amdgcn_s_setprio(1);
        #pragma unroll
        for (int rf = 0; rf < 6; ++rf) {
            bf16x8 a = *(const bf16x8*)(ab + rf * 512);
            #pragma unroll
            for (int i = 0; i < 4; ++i)
                acc[rf][i] = __builtin_amdgcn_mfma_f32_16x16x32_bf16(a, bfr[i], acc[rf][i], 0, 0, 0);
        }
        __builtin_amdgcn_s_setprio(0);

        if (ks < KSTEPS - 1) {
            u16x4 pk;   // compiler inserts vmcnt(4) here -> B(ks+1) stays in flight
            pk.x = f2bf(av.x); pk.y = f2bf(av.y); pk.z = f2bf(av.z); pk.w = f2bf(av.w);
            *(u16x4*)&aB[nxt * 3072 + awoff] = pk;
        }
        asm volatile("s_waitcnt lgkmcnt(0)" ::: "memory");
        __builtin_amdgcn_s_barrier();
    }

    // epilogue: per-row sum over this wave's 64 cols of gelu(h+b1)*w2
    int col16 = lane & 15, quart = lane >> 4;
    float b1v[4], w2v[4];
    #pragma unroll
    for (int i = 0; i < 4; ++i) {
        int c = cg * 64 + i * 16 + col16;
        b1v[i] = rb1[c]; w2v[i] = rw2[c];
    }
    #pragma unroll
    for (int rf = 0; rf < 6; ++rf) {
        #pragma unroll
        for (int r = 0; r < 4; ++r) {
            float s = 0.f;
            #pragma unroll
            for (int i = 0; i < 4; ++i)
                s += gelu_f(acc[rf][i][r] + b1v[i]) * w2v[i];
            #pragma unroll
            for (int m = 1; m < 16; m <<= 1) s += __shfl_xor(s, m);
            if (col16 == 0) part[wid * 96 + rf * 16 + quart * 4 + r] = s;
        }
    }
    __syncthreads();
    if (tid < 288) {
        int tt = tid / 96, row = tid % 96;
        float v = part[(tt * 4 + 0) * 96 + row] + part[(tt * 4 + 1) * 96 + row]
                + part[(tt * 4 + 2) * 96 + row] + part[(tt * 4 + 3) * 96 + row] + rb2[0];
        float p = 1.f / (1.f + __expf(-v));
        int rg = blk * BM + row;
        if (rg < NUM_EDGES) dprob[(size_t)tt * NUM_EDGES + rg] = p;
    }
}

// Kzero: zero raw accumulators e1..e3
__global__ void kzero(float* __restrict__ ws) {
    int i = blockIdx.x * 256 + threadIdx.x;
    if (i < 3 * NUM_ENT) ws[WS_E + NUM_ENT + i] = 0.f;
}

// K9: scatter step t: e_{t+1}[obj] += norm(e_t)[sub] * dprob[t][e]
// t==0: e0 is the topic indicator -- no gather needed.
__global__ void k9_scatter(const int* __restrict__ kb, const int* __restrict__ topics,
                           float* __restrict__ ws, int t) {
    int e = blockIdx.x * 256 + threadIdx.x;
    if (e >= NUM_EDGES) return;
    int sub = kb[2 * e], obj = kb[2 * e + 1];
    float g;
    if (t == 0) {
        g = (sub == topics[0] || sub == topics[1] || sub == topics[2] || sub == topics[3]) ? 1.f : 0.f;
    } else {
        float v = ws[WS_E + (size_t)t * NUM_ENT + sub];
        g = v / fmaxf(v, 1.f);
    }
    float p = g * ws[WS_DPROB + (size_t)t * NUM_EDGES + e];
    if (p != 0.f) atomicAdd(&ws[WS_E + (size_t)(t + 1) * NUM_ENT + obj], p);
}

// Kout: out[i] = sum_t hop_attn[t] * norm(e_{t+1})[i]
__global__ void kout(const float* __restrict__ ws, float* __restrict__ out) {
    int i = blockIdx.x * 256 + threadIdx.x;
    if (i >= NUM_ENT) return;
    float v1 = ws[WS_E + 1 * NUM_ENT + i]; v1 /= fmaxf(v1, 1.f);
    float v2 = ws[WS_E + 2 * NUM_ENT + i]; v2 /= fmaxf(v2, 1.f);
    float v3 = ws[WS_E + 3 * NUM_ENT + i]; v3 /= fmaxf(v3, 1.f);
    out[i] = ws[WS_HA + 0] * v1 + ws[WS_HA + 1] * v2 + ws[WS_HA + 2] * v3;
}

extern "C" void kernel_launch(void* const* d_in, const int* in_sizes, int n_in,
                              void* d_out, int out_size, void* d_ws, size_t ws_size,
                              hipStream_t stream) {
    const float* q_emb   = (const float*)d_in[0];
    const float* qwh     = (const float*)d_in[1];
    const float* desc    = (const float*)d_in[2];
    const float* sw1     = (const float*)d_in[3];
    const float* sb1     = (const float*)d_in[4];
    const float* sw2     = (const float*)d_in[5];
    const float* sb2     = (const float*)d_in[6];
    const float* rw1     = (const float*)d_in[7];
    const float* rb1     = (const float*)d_in[8];
    const float* rw2     = (const float*)d_in[9];
    const float* rb2     = (const float*)d_in[10];
    const float* hw1     = (const float*)d_in[11];
    const float* hb1     = (const float*)d_in[12];
    const float* hw2     = (const float*)d_in[13];
    const float* hb2     = (const float*)d_in[14];
    const int*   kb      = (const int*)d_in[15];
    const int*   topics  = (const int*)d_in[16];
    float* ws  = (float*)d_ws;
    float* out = (float*)d_out;

    int nblk7 = (NUM_EDGES + BM - 1) / BM;   // 2084

    kzero<<<(3 * NUM_ENT + 255) / 256, 256, 0, stream>>>(ws);
    k1a<<<64, 256, 0, stream>>>(q_emb, sw1, hw1, ws);
    k1b<<<10, 256, 0, stream>>>(sb1, hb1, ws);
    k2a<<<48, 256, 0, stream>>>(sw2, ws);
    k2b<<<9, 256, 0, stream>>>(sb2, ws);
    k345<<<1, 1024, 0, stream>>>(qwh, hw2, hb2, ws);
    k6_bmat<<<288, 256, 0, stream>>>(rw1, ws);
    k7_gemm<<<nblk7, 768, 115200, stream>>>(desc, rb1, rw2, rb2, ws);
    for (int t = 0; t < 3; ++t)
        k9_scatter<<<(NUM_EDGES + 255) / 256, 256, 0, stream>>>(kb, topics, ws, t);
    kout<<<(NUM_ENT + 255) / 256, 256, 0, stream>>>(ws, out);
}

// Round 4
// 540.476 us; speedup vs baseline: 2.2608x; 1.0020x over previous
//
#include <hip/hip_runtime.h>
#include <math.h>

#define NUM_ENT 100000
#define NUM_EDGES 200000
#define DIM 768
#define BM 96
#define KSTEPS 24
#define NC 16
#define DCH 48

typedef float f32x4 __attribute__((ext_vector_type(4)));
typedef __bf16 bf16x8 __attribute__((ext_vector_type(8)));
typedef unsigned short u16x4 __attribute__((ext_vector_type(4)));

// ---- ws layout (float indices) ----
#define WS_Y1    0        // 3*768
#define WS_CQ    2304     // 3*768
#define WS_HA    4704     // 3 hop_attn
#define WS_HOP1  4736     // 256
#define WS_CTX   4992     // 3*768
#define WS_B     7424     // bf16 frag-ordered: 24 chunks * 48 frags * 1KB
#define WS_DPROB 302336   // 3*200000 (also transient home of P1/P2 partials)
#define WS_P1    302336   // 48*768
#define WS_P1H   339200   // 16*256
#define WS_P2    343296   // 48*768
#define WS_E     902336   // 4*100000 (slot 0 unused; e1..e3 raw sums)

__device__ __forceinline__ unsigned short f2bf(float f) {
    unsigned int x = __builtin_bit_cast(unsigned int, f);
    x = x + 0x7fffu + ((x >> 16) & 1u);   // RTNE
    return (unsigned short)(x >> 16);
}

// A&S 7.1.26 erf approx, |eps| <= 1.5e-7
__device__ __forceinline__ float gelu_f(float x) {
    float z = 0.70710678118654752f * x;
    float s = fabsf(z);
    float t = 1.f / (1.f + 0.3275911f * s);
    float p = t * (0.254829592f + t * (-0.284496736f + t * (1.421413741f +
              t * (-1.453152027f + t * 1.061405429f))));
    float e = __expf(-s * s);
    float erfa = copysignf(1.f - p * e, z);
    return 0.5f * x * (1.f + erfa);
}

__device__ __forceinline__ void gload16(const void* g, void* l) {
    __builtin_amdgcn_global_load_lds(
        (const __attribute__((address_space(1))) void*)g,
        (__attribute__((address_space(3))) void*)l, 16, 0, 0);
}

// K1a: d-split partials for step layer-1 (48 blocks) and hop layer-1 (16 blocks)
__global__ void k1a(const float* __restrict__ q, const float* __restrict__ sw1,
                    const float* __restrict__ hw1, float* __restrict__ ws) {
    int b = blockIdx.x, tid = threadIdx.x;
    if (b < 48) {
        int t = b >> 4, c = b & 15;
        const float* w = sw1 + (size_t)t * DIM * DIM + (size_t)c * DCH * DIM;
        float a0 = 0.f, a1 = 0.f, a2 = 0.f;
        for (int d = 0; d < DCH; ++d) {
            float qv = q[c * DCH + d];
            const float* wr = w + (size_t)d * DIM;
            a0 += qv * wr[tid]; a1 += qv * wr[tid + 256]; a2 += qv * wr[tid + 512];
        }
        float* p = ws + WS_P1 + (size_t)b * DIM;
        p[tid] = a0; p[tid + 256] = a1; p[tid + 512] = a2;
    } else {
        int c = b - 48;
        const float* w = hw1 + (size_t)c * DCH * 256;
        float a0 = 0.f;
        for (int d = 0; d < DCH; ++d) a0 += q[c * DCH + d] * w[(size_t)d * 256 + tid];
        ws[WS_P1H + c * 256 + tid] = a0;
    }
}

// K1b: reduce partials + bias + gelu -> y1, hop1
__global__ void k1b(const float* __restrict__ sb1, const float* __restrict__ hb1,
                    float* __restrict__ ws) {
    int o = blockIdx.x * 256 + threadIdx.x;
    if (o < 2304) {
        int t = o / DIM, j = o % DIM;
        float s = sb1[o];
        for (int c = 0; c < NC; ++c) s += ws[WS_P1 + (size_t)(t * 16 + c) * DIM + j];
        ws[WS_Y1 + o] = gelu_f(s);
    } else if (o < 2560) {
        int j = o - 2304;
        float s = hb1[j];
        for (int c = 0; c < NC; ++c) s += ws[WS_P1H + c * 256 + j];
        ws[WS_HOP1 + j] = gelu_f(s);
    }
}

// K2a: d-split partials for step layer-2
__global__ void k2a(const float* __restrict__ sw2, float* __restrict__ ws) {
    int b = blockIdx.x, tid = threadIdx.x;
    int t = b >> 4, c = b & 15;
    const float* w = sw2 + (size_t)t * DIM * DIM + (size_t)c * DCH * DIM;
    const float* y = ws + WS_Y1 + t * DIM + c * DCH;
    float a0 = 0.f, a1 = 0.f, a2 = 0.f;
    for (int d = 0; d < DCH; ++d) {
        float yv = y[d];
        const float* wr = w + (size_t)d * DIM;
        a0 += yv * wr[tid]; a1 += yv * wr[tid + 256]; a2 += yv * wr[tid + 512];
    }
    float* p = ws + WS_P2 + (size_t)b * DIM;
    p[tid] = a0; p[tid + 256] = a1; p[tid + 512] = a2;
}

// K2b: reduce -> cq
__global__ void k2b(const float* __restrict__ sb2, float* __restrict__ ws) {
    int o = blockIdx.x * 256 + threadIdx.x;   // 0..2303
    int t = o / DIM, j = o % DIM;
    float s = sb2[o];
    for (int c = 0; c < NC; ++c) s += ws[WS_P2 + (size_t)(t * 16 + c) * DIM + j];
    ws[WS_CQ + o] = s;
}

// K345 (single block, 1024 thr): q_logits -> softmax -> ctx; hop_attn
__global__ void k345(const float* __restrict__ qwh, const float* __restrict__ hw2,
                     const float* __restrict__ hb2, float* __restrict__ ws) {
    __shared__ float qlog[96];
    int tid = threadIdx.x;
    int w = tid >> 6, lane = tid & 63;
    for (int s = 0; s < 6; ++s) {
        int p = w * 6 + s;
        int t = p >> 5, l = p & 31;
        const float* c = ws + WS_CQ + t * DIM;
        const float* qw = qwh + l * DIM;
        float acc = 0.f;
        for (int i = lane; i < DIM; i += 64) acc += c[i] * qw[i];
        for (int m = 32; m; m >>= 1) acc += __shfl_xor(acc, m);
        if (lane == 0) qlog[p] = acc;
    }
    __syncthreads();
    if (tid < 64) {
        for (int t = 0; t < 3; ++t) {
            float v = (lane < 32) ? qlog[t * 32 + lane] : -1e30f;
            float mx = v;
            for (int m = 1; m < 32; m <<= 1) mx = fmaxf(mx, __shfl_xor(mx, m, 32));
            float e = (lane < 32) ? __expf(v - mx) : 0.f;
            float s = e;
            for (int m = 1; m < 32; m <<= 1) s += __shfl_xor(s, m, 32);
            if (lane < 32) qlog[t * 32 + lane] = e / s;
        }
        float lg = 0.f;
        if (lane < 3) {
            for (int s = 0; s < 256; ++s) lg += ws[WS_HOP1 + s] * hw2[s * 3 + lane];
            lg += hb2[lane];
        }
        float l0 = __shfl(lg, 0), l1 = __shfl(lg, 1), l2 = __shfl(lg, 2);
        if (lane == 0) {
            float mx = fmaxf(l0, fmaxf(l1, l2));
            float e0 = __expf(l0 - mx), e1 = __expf(l1 - mx), e2 = __expf(l2 - mx);
            float s = e0 + e1 + e2;
            ws[WS_HA + 0] = e0 / s; ws[WS_HA + 1] = e1 / s; ws[WS_HA + 2] = e2 / s;
        }
    }
    __syncthreads();
    for (int o = tid; o < 2304; o += 1024) {
        int t = o / DIM, d = o % DIM;
        float acc = ws[WS_CQ + o];
        const float* qd = qlog + t * 32;
        for (int l = 0; l < 32; ++l) acc += qd[l] * qwh[l * DIM + d];
        ws[WS_CTX + o] = acc;
    }
}

// K6: B bf16, K-chunk-major frag order: chunk ks (0..23) holds 48 frags (t*16+cf)
__global__ void k6_bmat(const float* __restrict__ rw1, float* __restrict__ ws) {
    int g = blockIdx.x * 256 + threadIdx.x;   // 0..73727
    int lane = g & 63, f = g >> 6;            // f 0..1151
    int ks = f / 48, r = f % 48;
    int t = r >> 4, cf = r & 15;
    int k0 = ks * 32 + (lane >> 4) * 8;
    int col = cf * 16 + (lane & 15);
    const float* ctx = ws + WS_CTX + t * DIM;
    union { unsigned short u[8]; bf16x8 v; } pk;
    #pragma unroll
    for (int j = 0; j < 8; ++j) {
        float v = ctx[k0 + j] * rw1[(size_t)(k0 + j) * 256 + col];
        pk.u[j] = f2bf(v);
    }
    *(bf16x8*)((unsigned short*)(ws + WS_B) + (size_t)g * 8) = pk.v;
}

// K7: counted-vmcnt pipelined GEMM + fused epilogue -> dprob[t][edge]
// BM=96, BN=768 (3t x 256), BK=32, 768 thr = 12 waves (wid = t*4+cg).
// Wave wid consumes exactly the B frags it stages (fbase==4*wid) -> no B barrier.
// NEW: per-block K-stagger (ks0 = blk % 24). Accumulation over K is commutative;
// staggering spreads the 256 CUs' B-chunk DMA across all 24 chunks instead of
// hammering the same 48KB L2 lines in lockstep (the suspected 6.4K-cyc/kstep stall).
// LDS: bbuf 2x48KB @0, abuf 2x6KB @98304, part 12x96 f32 @110592 (115200 B)
__global__ __launch_bounds__(768, 3)
void k7_gemm(const float* __restrict__ desc, const float* __restrict__ rb1,
             const float* __restrict__ rw2, const float* __restrict__ rb2,
             float* __restrict__ ws) {
    extern __shared__ char lds[];
    unsigned short* bB = (unsigned short*)lds;               // 2 * 24576 ushort
    unsigned short* aB = (unsigned short*)(lds + 98304);     // 2 * 3072 ushort
    float* part = (float*)(lds + 110592);                    // 12 * 96

    const unsigned short* bmat = (const unsigned short*)(ws + WS_B);
    float* dprob = ws + WS_DPROB;
    int tid = threadIdx.x;
    int blk = blockIdx.x;
    int wid = tid >> 6, lane = tid & 63;
    int t = wid >> 2, cg = wid & 3;
    int fbase = t * 16 + cg * 4;   // == 4*wid
    int ks0 = blk % KSTEPS;        // K-stagger offset

    // A staging indexing: thread -> (row, float4-quad)
    int arow = tid >> 3, aq = tid & 7;
    int rowg = blk * BM + arow;
    if (rowg > NUM_EDGES - 1) rowg = NUM_EDGES - 1;
    const float* asrc = desc + (size_t)rowg * DIM + aq * 4;
    int arf = arow >> 4, alr = arow & 15;
    int awoff = arf * 512 + (aq >> 1) * 128 + alr * 8 + (aq & 1) * 4; // ushort off

    // B staging: wave-uniform LDS base; per-lane global source
    const char* bsrc0 = (const char*)bmat + wid * 4096 + lane * 16;
    char* bdst0 = (char*)bB + wid * 4096;

    f32x4 acc[6][4];
    #pragma unroll
    for (int rf = 0; rf < 6; ++rf)
        #pragma unroll
        for (int i = 0; i < 4; ++i) acc[rf][i] = f32x4{0.f, 0.f, 0.f, 0.f};

    // prologue: A(ks0) reg-load first, then B(ks0) DMA
    {
        float4 av = *(const float4*)(asrc + ks0 * 32);
        #pragma unroll
        for (int j = 0; j < 4; ++j)
            gload16(bsrc0 + (size_t)ks0 * 49152 + j * 1024, bdst0 + j * 1024);
        u16x4 pk;
        pk.x = f2bf(av.x); pk.y = f2bf(av.y); pk.z = f2bf(av.z); pk.w = f2bf(av.w);
        *(u16x4*)&aB[awoff] = pk;
    }
    asm volatile("s_waitcnt lgkmcnt(0)" ::: "memory");
    __builtin_amdgcn_s_barrier();

    #pragma unroll 1
    for (int it = 0; it < KSTEPS; ++it) {
        int cur = it & 1, nxt = cur ^ 1;
        float4 av;
        if (it < KSTEPS - 1) {
            int ksn = ks0 + it + 1;
            if (ksn >= KSTEPS) ksn -= KSTEPS;
            av = *(const float4*)(asrc + ksn * 32);            // oldest this iter
            const char* bs = bsrc0 + (size_t)ksn * 49152;
            char* bd = bdst0 + nxt * 49152;
            #pragma unroll
            for (int j = 0; j < 4; ++j) gload16(bs + j * 1024, bd + j * 1024);
            // outstanding: B(it) x4 (oldest) + av + B(it+1) x4 -> keep 5 in flight
            asm volatile("s_waitcnt vmcnt(5)" ::: "memory");
        } else {
            asm volatile("s_waitcnt vmcnt(0)" ::: "memory");
        }
        __builtin_amdgcn_sched_barrier(0);

        const unsigned short* bb = bB + cur * 24576 + fbase * 512 + lane * 8;
        bf16x8 bfr[4];
        #pragma unroll
        for (int i = 0; i < 4; ++i) bfr[i] = *(const bf16x8*)(bb + i * 512);
        const unsigned short* ab = aB + cur * 3072 + lane * 8;

        __builtin_amdgcn_s_setprio(1);
        #pragma unroll
        for (int rf = 0; rf < 6; ++rf) {
            bf16x8 a = *(const bf16x8*)(ab + rf * 512);
            #pragma unroll
            for (int i = 0; i < 4; ++i)
                acc[rf][i] = __builtin_amdgcn_mfma_f32_16x16x32_bf16(a, bfr[i], acc[rf][i], 0, 0, 0);
        }
        __builtin_amdgcn_s_setprio(0);

        if (it < KSTEPS - 1) {
            u16x4 pk;   // compiler's wait here leaves B(it+1) in flight
            pk.x = f2bf(av.x); pk.y = f2bf(av.y); pk.z = f2bf(av.z); pk.w = f2bf(av.w);
            *(u16x4*)&aB[nxt * 3072 + awoff] = pk;
        }
        asm volatile("s_waitcnt lgkmcnt(0)" ::: "memory");
        __builtin_amdgcn_s_barrier();
    }

    // epilogue: per-row sum over this wave's 64 cols of gelu(h+b1)*w2
    int col16 = lane & 15, quart = lane >> 4;
    float b1v[4], w2v[4];
    #pragma unroll
    for (int i = 0; i < 4; ++i) {
        int c = cg * 64 + i * 16 + col16;
        b1v[i] = rb1[c]; w2v[i] = rw2[c];
    }
    #pragma unroll
    for (int rf = 0; rf < 6; ++rf) {
        #pragma unroll
        for (int r = 0; r < 4; ++r) {
            float s = 0.f;
            #pragma unroll
            for (int i = 0; i < 4; ++i)
                s += gelu_f(acc[rf][i][r] + b1v[i]) * w2v[i];
            #pragma unroll
            for (int m = 1; m < 16; m <<= 1) s += __shfl_xor(s, m);
            if (col16 == 0) part[wid * 96 + rf * 16 + quart * 4 + r] = s;
        }
    }
    __syncthreads();
    if (tid < 288) {
        int tt = tid / 96, row = tid % 96;
        float v = part[(tt * 4 + 0) * 96 + row] + part[(tt * 4 + 1) * 96 + row]
                + part[(tt * 4 + 2) * 96 + row] + part[(tt * 4 + 3) * 96 + row] + rb2[0];
        float p = 1.f / (1.f + __expf(-v));
        int rg = blk * BM + row;
        if (rg < NUM_EDGES) dprob[(size_t)tt * NUM_EDGES + rg] = p;
    }
}

// Kzero: zero raw accumulators e1..e3
__global__ void kzero(float* __restrict__ ws) {
    int i = blockIdx.x * 256 + threadIdx.x;
    if (i < 3 * NUM_ENT) ws[WS_E + NUM_ENT + i] = 0.f;
}

// K9: scatter step t: e_{t+1}[obj] += norm(e_t)[sub] * dprob[t][e]
// t==0: e0 is the topic indicator -- no gather needed.
__global__ void k9_scatter(const int* __restrict__ kb, const int* __restrict__ topics,
                           float* __restrict__ ws, int t) {
    int e = blockIdx.x * 256 + threadIdx.x;
    if (e >= NUM_EDGES) return;
    int sub = kb[2 * e], obj = kb[2 * e + 1];
    float g;
    if (t == 0) {
        g = (sub == topics[0] || sub == topics[1] || sub == topics[2] || sub == topics[3]) ? 1.f : 0.f;
    } else {
        float v = ws[WS_E + (size_t)t * NUM_ENT + sub];
        g = v / fmaxf(v, 1.f);
    }
    float p = g * ws[WS_DPROB + (size_t)t * NUM_EDGES + e];
    if (p != 0.f) atomicAdd(&ws[WS_E + (size_t)(t + 1) * NUM_ENT + obj], p);
}

// Kout: out[i] = sum_t hop_attn[t] * norm(e_{t+1})[i]
__global__ void kout(const float* __restrict__ ws, float* __restrict__ out) {
    int i = blockIdx.x * 256 + threadIdx.x;
    if (i >= NUM_ENT) return;
    float v1 = ws[WS_E + 1 * NUM_ENT + i]; v1 /= fmaxf(v1, 1.f);
    float v2 = ws[WS_E + 2 * NUM_ENT + i]; v2 /= fmaxf(v2, 1.f);
    float v3 = ws[WS_E + 3 * NUM_ENT + i]; v3 /= fmaxf(v3, 1.f);
    out[i] = ws[WS_HA + 0] * v1 + ws[WS_HA + 1] * v2 + ws[WS_HA + 2] * v3;
}

extern "C" void kernel_launch(void* const* d_in, const int* in_sizes, int n_in,
                              void* d_out, int out_size, void* d_ws, size_t ws_size,
                              hipStream_t stream) {
    const float* q_emb   = (const float*)d_in[0];
    const float* qwh     = (const float*)d_in[1];
    const float* desc    = (const float*)d_in[2];
    const float* sw1     = (const float*)d_in[3];
    const float* sb1     = (const float*)d_in[4];
    const float* sw2     = (const float*)d_in[5];
    const float* sb2     = (const float*)d_in[6];
    const float* rw1     = (const float*)d_in[7];
    const float* rb1     = (const float*)d_in[8];
    const float* rw2     = (const float*)d_in[9];
    const float* rb2     = (const float*)d_in[10];
    const float* hw1     = (const float*)d_in[11];
    const float* hb1     = (const float*)d_in[12];
    const float* hw2     = (const float*)d_in[13];
    const float* hb2     = (const float*)d_in[14];
    const int*   kb      = (const int*)d_in[15];
    const int*   topics  = (const int*)d_in[16];
    float* ws  = (float*)d_ws;
    float* out = (float*)d_out;

    int nblk7 = (NUM_EDGES + BM - 1) / BM;   // 2084

    kzero<<<(3 * NUM_ENT + 255) / 256, 256, 0, stream>>>(ws);
    k1a<<<64, 256, 0, stream>>>(q_emb, sw1, hw1, ws);
    k1b<<<10, 256, 0, stream>>>(sb1, hb1, ws);
    k2a<<<48, 256, 0, stream>>>(sw2, ws);
    k2b<<<9, 256, 0, stream>>>(sb2, ws);
    k345<<<1, 1024, 0, stream>>>(qwh, hw2, hb2, ws);
    k6_bmat<<<288, 256, 0, stream>>>(rw1, ws);
    k7_gemm<<<nblk7, 768, 115200, stream>>>(desc, rb1, rw2, rb2, ws);
    for (int t = 0; t < 3; ++t)
        k9_scatter<<<(NUM_EDGES + 255) / 256, 256, 0, stream>>>(kb, topics, ws, t);
    kout<<<(NUM_ENT + 255) / 256, 256, 0, stream>>>(ws, out);
}

// Round 5
// 463.460 us; speedup vs baseline: 2.6365x; 1.1662x over previous
//
#include <hip/hip_runtime.h>
#include <math.h>

#define NUM_ENT 100000
#define NUM_EDGES 200000
#define DIM 768
#define BM 64
#define KSTEPS 24
#define NC 16
#define DCH 48

typedef float f32x4 __attribute__((ext_vector_type(4)));
typedef __bf16 bf16x8 __attribute__((ext_vector_type(8)));

// ---- ws layout (float indices) ----
#define WS_Y1    0        // 3*768
#define WS_CQ    2304     // 3*768
#define WS_HA    4704     // 3 hop_attn
#define WS_HOP1  4736     // 256
#define WS_CTX   4992     // 3*768
#define WS_B     7424     // bf16 frag-ordered: 24 chunks * 48 frags * 1KB
#define WS_DPROB 302336   // 3*200000 (also transient home of P1/P2 partials)
#define WS_P1    302336   // 48*768
#define WS_P1H   339200   // 16*256
#define WS_P2    343296   // 48*768
#define WS_E     902336   // 4*100000 (slot 0 unused; e1..e3 raw sums)

__device__ __forceinline__ unsigned short f2bf(float f) {
    unsigned int x = __builtin_bit_cast(unsigned int, f);
    x = x + 0x7fffu + ((x >> 16) & 1u);   // RTNE
    return (unsigned short)(x >> 16);
}

// A&S 7.1.26 erf approx, |eps| <= 1.5e-7
__device__ __forceinline__ float gelu_f(float x) {
    float z = 0.70710678118654752f * x;
    float s = fabsf(z);
    float t = 1.f / (1.f + 0.3275911f * s);
    float p = t * (0.254829592f + t * (-0.284496736f + t * (1.421413741f +
              t * (-1.453152027f + t * 1.061405429f))));
    float e = __expf(-s * s);
    float erfa = copysignf(1.f - p * e, z);
    return 0.5f * x * (1.f + erfa);
}

// K1a: d-split partials for step layer-1 (48 blocks) and hop layer-1 (16 blocks)
__global__ void k1a(const float* __restrict__ q, const float* __restrict__ sw1,
                    const float* __restrict__ hw1, float* __restrict__ ws) {
    int b = blockIdx.x, tid = threadIdx.x;
    if (b < 48) {
        int t = b >> 4, c = b & 15;
        const float* w = sw1 + (size_t)t * DIM * DIM + (size_t)c * DCH * DIM;
        float a0 = 0.f, a1 = 0.f, a2 = 0.f;
        for (int d = 0; d < DCH; ++d) {
            float qv = q[c * DCH + d];
            const float* wr = w + (size_t)d * DIM;
            a0 += qv * wr[tid]; a1 += qv * wr[tid + 256]; a2 += qv * wr[tid + 512];
        }
        float* p = ws + WS_P1 + (size_t)b * DIM;
        p[tid] = a0; p[tid + 256] = a1; p[tid + 512] = a2;
    } else {
        int c = b - 48;
        const float* w = hw1 + (size_t)c * DCH * 256;
        float a0 = 0.f;
        for (int d = 0; d < DCH; ++d) a0 += q[c * DCH + d] * w[(size_t)d * 256 + tid];
        ws[WS_P1H + c * 256 + tid] = a0;
    }
}

// K1b: reduce partials + bias + gelu -> y1, hop1
__global__ void k1b(const float* __restrict__ sb1, const float* __restrict__ hb1,
                    float* __restrict__ ws) {
    int o = blockIdx.x * 256 + threadIdx.x;
    if (o < 2304) {
        int t = o / DIM, j = o % DIM;
        float s = sb1[o];
        for (int c = 0; c < NC; ++c) s += ws[WS_P1 + (size_t)(t * 16 + c) * DIM + j];
        ws[WS_Y1 + o] = gelu_f(s);
    } else if (o < 2560) {
        int j = o - 2304;
        float s = hb1[j];
        for (int c = 0; c < NC; ++c) s += ws[WS_P1H + c * 256 + j];
        ws[WS_HOP1 + j] = gelu_f(s);
    }
}

// K2a: d-split partials for step layer-2
__global__ void k2a(const float* __restrict__ sw2, float* __restrict__ ws) {
    int b = blockIdx.x, tid = threadIdx.x;
    int t = b >> 4, c = b & 15;
    const float* w = sw2 + (size_t)t * DIM * DIM + (size_t)c * DCH * DIM;
    const float* y = ws + WS_Y1 + t * DIM + c * DCH;
    float a0 = 0.f, a1 = 0.f, a2 = 0.f;
    for (int d = 0; d < DCH; ++d) {
        float yv = y[d];
        const float* wr = w + (size_t)d * DIM;
        a0 += yv * wr[tid]; a1 += yv * wr[tid + 256]; a2 += yv * wr[tid + 512];
    }
    float* p = ws + WS_P2 + (size_t)b * DIM;
    p[tid] = a0; p[tid + 256] = a1; p[tid + 512] = a2;
}

// K2b: reduce -> cq
__global__ void k2b(const float* __restrict__ sb2, float* __restrict__ ws) {
    int o = blockIdx.x * 256 + threadIdx.x;   // 0..2303
    int t = o / DIM, j = o % DIM;
    float s = sb2[o];
    for (int c = 0; c < NC; ++c) s += ws[WS_P2 + (size_t)(t * 16 + c) * DIM + j];
    ws[WS_CQ + o] = s;
}

// K345 (single block, 1024 thr): q_logits -> softmax -> ctx; hop_attn
__global__ void k345(const float* __restrict__ qwh, const float* __restrict__ hw2,
                     const float* __restrict__ hb2, float* __restrict__ ws) {
    __shared__ float qlog[96];
    int tid = threadIdx.x;
    int w = tid >> 6, lane = tid & 63;
    for (int s = 0; s < 6; ++s) {
        int p = w * 6 + s;
        int t = p >> 5, l = p & 31;
        const float* c = ws + WS_CQ + t * DIM;
        const float* qw = qwh + l * DIM;
        float acc = 0.f;
        for (int i = lane; i < DIM; i += 64) acc += c[i] * qw[i];
        for (int m = 32; m; m >>= 1) acc += __shfl_xor(acc, m);
        if (lane == 0) qlog[p] = acc;
    }
    __syncthreads();
    if (tid < 64) {
        for (int t = 0; t < 3; ++t) {
            float v = (lane < 32) ? qlog[t * 32 + lane] : -1e30f;
            float mx = v;
            for (int m = 1; m < 32; m <<= 1) mx = fmaxf(mx, __shfl_xor(mx, m, 32));
            float e = (lane < 32) ? __expf(v - mx) : 0.f;
            float s = e;
            for (int m = 1; m < 32; m <<= 1) s += __shfl_xor(s, m, 32);
            if (lane < 32) qlog[t * 32 + lane] = e / s;
        }
        float lg = 0.f;
        if (lane < 3) {
            for (int s = 0; s < 256; ++s) lg += ws[WS_HOP1 + s] * hw2[s * 3 + lane];
            lg += hb2[lane];
        }
        float l0 = __shfl(lg, 0), l1 = __shfl(lg, 1), l2 = __shfl(lg, 2);
        if (lane == 0) {
            float mx = fmaxf(l0, fmaxf(l1, l2));
            float e0 = __expf(l0 - mx), e1 = __expf(l1 - mx), e2 = __expf(l2 - mx);
            float s = e0 + e1 + e2;
            ws[WS_HA + 0] = e0 / s; ws[WS_HA + 1] = e1 / s; ws[WS_HA + 2] = e2 / s;
        }
    }
    __syncthreads();
    for (int o = tid; o < 2304; o += 1024) {
        int t = o / DIM, d = o % DIM;
        float acc = ws[WS_CQ + o];
        const float* qd = qlog + t * 32;
        for (int l = 0; l < 32; ++l) acc += qd[l] * qwh[l * DIM + d];
        ws[WS_CTX + o] = acc;
    }
}

// K6: B bf16, K-chunk-major frag order: chunk ks (0..23) holds 48 frags (t*16+cf)
__global__ void k6_bmat(const float* __restrict__ rw1, float* __restrict__ ws) {
    int g = blockIdx.x * 256 + threadIdx.x;   // 0..73727
    int lane = g & 63, f = g >> 6;            // f 0..1151
    int ks = f / 48, r = f % 48;
    int t = r >> 4, cf = r & 15;
    int k0 = ks * 32 + (lane >> 4) * 8;
    int col = cf * 16 + (lane & 15);
    const float* ctx = ws + WS_CTX + t * DIM;
    union { unsigned short u[8]; bf16x8 v; } pk;
    #pragma unroll
    for (int j = 0; j < 8; ++j) {
        float v = ctx[k0 + j] * rw1[(size_t)(k0 + j) * 256 + col];
        pk.u[j] = f2bf(v);
    }
    *(bf16x8*)((unsigned short*)(ws + WS_B) + (size_t)g * 8) = pk.v;
}

#define MFMA4(A, B0, B1, B2, B3, RF)                                               \
    acc[RF][0] = __builtin_amdgcn_mfma_f32_16x16x32_bf16(A, B0, acc[RF][0], 0,0,0); \
    acc[RF][1] = __builtin_amdgcn_mfma_f32_16x16x32_bf16(A, B1, acc[RF][1], 0,0,0); \
    acc[RF][2] = __builtin_amdgcn_mfma_f32_16x16x32_bf16(A, B2, acc[RF][2], 0,0,0); \
    acc[RF][3] = __builtin_amdgcn_mfma_f32_16x16x32_bf16(A, B3, acc[RF][3], 0,0,0);

// K7: barrier-free K-loop GEMM + fused epilogue -> dprob[t][edge]
// BM=64 rows, BN=768 (3t x 256), BK=32, 768 thr = 12 waves (wid = t*4+cg).
// A: staged bf16 in LDS ONCE per block (96 KB), read-only in the K-loop.
// B: per-wave direct global->VGPR, double-buffered one kstep ahead (each frag
//    read exactly once per block). NO barriers / NO LDS writes / NO repack in
//    the K-loop -> waves drift freely, phases overlap across waves.
// LDS: A 98304 B @0, part 12x64 f32 @98304 (101376 B total)
__global__ __launch_bounds__(768, 3)
void k7_gemm(const float* __restrict__ desc, const float* __restrict__ rb1,
             const float* __restrict__ rw2, const float* __restrict__ rb2,
             float* __restrict__ ws) {
    extern __shared__ char lds[];
    unsigned short* aLds = (unsigned short*)lds;   // 96 frags * 512 ushort
    float* part = (float*)(lds + 98304);           // 12 * 64

    const unsigned short* bmat = (const unsigned short*)(ws + WS_B);
    float* dprob = ws + WS_DPROB;
    int tid = threadIdx.x, blk = blockIdx.x;
    int wid = tid >> 6, lane = tid & 63;
    int t = wid >> 2, cg = wid & 3;
    int fbase = (t << 4) + (cg << 2);   // this wave's 4 B-frags per kstep

    // ---- B(0) prefetch into registers (completes while A stages) ----
    const unsigned short* bp = bmat + ((size_t)fbase << 9) + lane * 8;
    bf16x8 b0_0 = *(const bf16x8*)(bp);
    bf16x8 b0_1 = *(const bf16x8*)(bp + 512);
    bf16x8 b0_2 = *(const bf16x8*)(bp + 1024);
    bf16x8 b0_3 = *(const bf16x8*)(bp + 1536);
    bp += 48 * 512;

    // ---- one-time A stage: f32 -> bf16, MFMA-fragment order ----
    #pragma unroll
    for (int i = 0; i < 8; ++i) {
        int gf = i * 768 + tid;            // 0..6143 slots (96 frags x 64 lanes)
        int l = gf & 63, f = gf >> 6;      // f = ks*4 + rf
        int ks = f >> 2, rf = f & 3;
        int row = rf * 16 + (l & 15);
        int kb = ks * 32 + (l >> 4) * 8;
        const float* src = desc + (size_t)(blk * BM + row) * DIM + kb;
        float4 v0 = *(const float4*)src;
        float4 v1 = *(const float4*)(src + 4);
        bf16x8 pk;
        pk[0] = (__bf16)v0.x; pk[1] = (__bf16)v0.y; pk[2] = (__bf16)v0.z; pk[3] = (__bf16)v0.w;
        pk[4] = (__bf16)v1.x; pk[5] = (__bf16)v1.y; pk[6] = (__bf16)v1.z; pk[7] = (__bf16)v1.w;
        *(bf16x8*)(aLds + (size_t)f * 512 + l * 8) = pk;
    }
    __syncthreads();

    f32x4 acc[4][4];
    #pragma unroll
    for (int rf = 0; rf < 4; ++rf)
        #pragma unroll
        for (int i = 0; i < 4; ++i) acc[rf][i] = f32x4{0.f, 0.f, 0.f, 0.f};

    const unsigned short* ab0 = aLds + lane * 8;
    bf16x8 b1_0, b1_1, b1_2, b1_3;

    #pragma unroll 1
    for (int ks = 0; ks < KSTEPS; ks += 2) {
        // issue next-kstep B loads (compiler inserts the counted vmcnt)
        b1_0 = *(const bf16x8*)(bp);
        b1_1 = *(const bf16x8*)(bp + 512);
        b1_2 = *(const bf16x8*)(bp + 1024);
        b1_3 = *(const bf16x8*)(bp + 1536);
        bp += 48 * 512;
        {
            const unsigned short* ab = ab0 + (size_t)ks * 2048;
            bf16x8 a;
            a = *(const bf16x8*)(ab);          MFMA4(a, b0_0, b0_1, b0_2, b0_3, 0)
            a = *(const bf16x8*)(ab + 512);    MFMA4(a, b0_0, b0_1, b0_2, b0_3, 1)
            a = *(const bf16x8*)(ab + 1024);   MFMA4(a, b0_0, b0_1, b0_2, b0_3, 2)
            a = *(const bf16x8*)(ab + 1536);   MFMA4(a, b0_0, b0_1, b0_2, b0_3, 3)
        }
        if (ks + 2 < KSTEPS) {
            b0_0 = *(const bf16x8*)(bp);
            b0_1 = *(const bf16x8*)(bp + 512);
            b0_2 = *(const bf16x8*)(bp + 1024);
            b0_3 = *(const bf16x8*)(bp + 1536);
            bp += 48 * 512;
        }
        {
            const unsigned short* ab = ab0 + (size_t)ks * 2048 + 2048;
            bf16x8 a;
            a = *(const bf16x8*)(ab);          MFMA4(a, b1_0, b1_1, b1_2, b1_3, 0)
            a = *(const bf16x8*)(ab + 512);    MFMA4(a, b1_0, b1_1, b1_2, b1_3, 1)
            a = *(const bf16x8*)(ab + 1024);   MFMA4(a, b1_0, b1_1, b1_2, b1_3, 2)
            a = *(const bf16x8*)(ab + 1536);   MFMA4(a, b1_0, b1_1, b1_2, b1_3, 3)
        }
    }

    // epilogue: per-row sum over this wave's 64 cols of gelu(h+b1)*w2
    int col16 = lane & 15, quart = lane >> 4;
    float b1v[4], w2v[4];
    #pragma unroll
    for (int i = 0; i < 4; ++i) {
        int c = cg * 64 + i * 16 + col16;
        b1v[i] = rb1[c]; w2v[i] = rw2[c];
    }
    #pragma unroll
    for (int rf = 0; rf < 4; ++rf) {
        #pragma unroll
        for (int r = 0; r < 4; ++r) {
            float s = 0.f;
            #pragma unroll
            for (int i = 0; i < 4; ++i)
                s += gelu_f(acc[rf][i][r] + b1v[i]) * w2v[i];
            #pragma unroll
            for (int m = 1; m < 16; m <<= 1) s += __shfl_xor(s, m);
            if (col16 == 0) part[wid * 64 + rf * 16 + quart * 4 + r] = s;
        }
    }
    __syncthreads();
    if (tid < 192) {
        int tt = tid >> 6, row = tid & 63;
        float v = part[(tt * 4 + 0) * 64 + row] + part[(tt * 4 + 1) * 64 + row]
                + part[(tt * 4 + 2) * 64 + row] + part[(tt * 4 + 3) * 64 + row] + rb2[0];
        float p = 1.f / (1.f + __expf(-v));
        dprob[(size_t)tt * NUM_EDGES + blk * BM + row] = p;
    }
}

// Kzero: zero raw accumulators e1..e3
__global__ void kzero(float* __restrict__ ws) {
    int i = blockIdx.x * 256 + threadIdx.x;
    if (i < 3 * NUM_ENT) ws[WS_E + NUM_ENT + i] = 0.f;
}

// K9: scatter step t: e_{t+1}[obj] += norm(e_t)[sub] * dprob[t][e]
// t==0: e0 is the topic indicator -- no gather needed.
__global__ void k9_scatter(const int* __restrict__ kb, const int* __restrict__ topics,
                           float* __restrict__ ws, int t) {
    int e = blockIdx.x * 256 + threadIdx.x;
    if (e >= NUM_EDGES) return;
    int sub = kb[2 * e], obj = kb[2 * e + 1];
    float g;
    if (t == 0) {
        g = (sub == topics[0] || sub == topics[1] || sub == topics[2] || sub == topics[3]) ? 1.f : 0.f;
    } else {
        float v = ws[WS_E + (size_t)t * NUM_ENT + sub];
        g = v / fmaxf(v, 1.f);
    }
    float p = g * ws[WS_DPROB + (size_t)t * NUM_EDGES + e];
    if (p != 0.f) atomicAdd(&ws[WS_E + (size_t)(t + 1) * NUM_ENT + obj], p);
}

// Kout: out[i] = sum_t hop_attn[t] * norm(e_{t+1})[i]
__global__ void kout(const float* __restrict__ ws, float* __restrict__ out) {
    int i = blockIdx.x * 256 + threadIdx.x;
    if (i >= NUM_ENT) return;
    float v1 = ws[WS_E + 1 * NUM_ENT + i]; v1 /= fmaxf(v1, 1.f);
    float v2 = ws[WS_E + 2 * NUM_ENT + i]; v2 /= fmaxf(v2, 1.f);
    float v3 = ws[WS_E + 3 * NUM_ENT + i]; v3 /= fmaxf(v3, 1.f);
    out[i] = ws[WS_HA + 0] * v1 + ws[WS_HA + 1] * v2 + ws[WS_HA + 2] * v3;
}

extern "C" void kernel_launch(void* const* d_in, const int* in_sizes, int n_in,
                              void* d_out, int out_size, void* d_ws, size_t ws_size,
                              hipStream_t stream) {
    const float* q_emb   = (const float*)d_in[0];
    const float* qwh     = (const float*)d_in[1];
    const float* desc    = (const float*)d_in[2];
    const float* sw1     = (const float*)d_in[3];
    const float* sb1     = (const float*)d_in[4];
    const float* sw2     = (const float*)d_in[5];
    const float* sb2     = (const float*)d_in[6];
    const float* rw1     = (const float*)d_in[7];
    const float* rb1     = (const float*)d_in[8];
    const float* rw2     = (const float*)d_in[9];
    const float* rb2     = (const float*)d_in[10];
    const float* hw1     = (const float*)d_in[11];
    const float* hb1     = (const float*)d_in[12];
    const float* hw2     = (const float*)d_in[13];
    const float* hb2     = (const float*)d_in[14];
    const int*   kb      = (const int*)d_in[15];
    const int*   topics  = (const int*)d_in[16];
    float* ws  = (float*)d_ws;
    float* out = (float*)d_out;

    int nblk7 = NUM_EDGES / BM;   // 3125, exact

    kzero<<<(3 * NUM_ENT + 255) / 256, 256, 0, stream>>>(ws);
    k1a<<<64, 256, 0, stream>>>(q_emb, sw1, hw1, ws);
    k1b<<<10, 256, 0, stream>>>(sb1, hb1, ws);
    k2a<<<48, 256, 0, stream>>>(sw2, ws);
    k2b<<<9, 256, 0, stream>>>(sb2, ws);
    k345<<<1, 1024, 0, stream>>>(qwh, hw2, hb2, ws);
    k6_bmat<<<288, 256, 0, stream>>>(rw1, ws);
    k7_gemm<<<nblk7, 768, 101376, stream>>>(desc, rb1, rw2, rb2, ws);
    for (int t = 0; t < 3; ++t)
        k9_scatter<<<(NUM_EDGES + 255) / 256, 256, 0, stream>>>(kb, topics, ws, t);
    kout<<<(NUM_ENT + 255) / 256, 256, 0, stream>>>(ws, out);
}